// Round 14
// baseline (535.928 us; speedup 1.0000x reference)
//
#include <hip/hip_runtime.h>
#include <hip/hip_bf16.h>

// Problem constants
#define NTOT 65536      // B*N
#define KNN  20
#define KROW 104        // bf16 kf row stride (67 dims + pad)

typedef __attribute__((ext_vector_type(4))) float f32x4;
typedef __attribute__((ext_vector_type(8))) short s16x8;

// ws layout (bytes): kfB bf16[65536][104] | normB f32[65536] | (unused) |
//                    wb1 bf16[16384] | wb2 bf16[16384] | mg u16[16384*32]
#define WS_NORM 13631488
#define WS_WT1  15204352
#define WS_WT2  15237120
#define WS_MG   15269888    // 1 MB; ws end = 16318464 < 16 MiB

// ---- k_knn LDS map (bytes) ----
// buf: 144 rows x 257 dwords (256 columns + 1 pad for bank spread) = 148032
// col = qLocal*4 + kq   (qLocal 0..63 within block, kq = key quarter 0..3)
#define ROWS 144
#define CSTR 257
#define OFF_TAUG 149056     // unsigned tauG[64]
#define KNN_SMEM 149312
#define THRESH 64           // compact a column when cnt > THRESH (max cn <= 144)

__device__ __forceinline__ unsigned short f2bf_rne(float v){
  unsigned u = __float_as_uint(v);
  return (unsigned short)((u + 0x7FFFu + ((u >> 16) & 1u)) >> 16);
}

// ---------------------------------------------------------------------------
// k_prep: kf = [s(16), R^T v(48), pos(3)] -> bf16 rows (stride 104) + f32 norm
// ---------------------------------------------------------------------------
__global__ __launch_bounds__(256) void k_prep(const float* __restrict__ x,
        const float* __restrict__ pos, const float* __restrict__ lfr,
        unsigned short* __restrict__ kfB, float* __restrict__ normB){
  int n = blockIdx.x * 256 + threadIdx.x;
  const float* xr = x + n * 64;
  float R[9];
  #pragma unroll
  for (int j = 0; j < 9; j++) R[j] = lfr[n * 9 + j];
  float c[67];
  #pragma unroll
  for (int i = 0; i < 16; i++) c[i] = xr[i];
  #pragma unroll
  for (int k = 0; k < 16; k++){
    float v0 = xr[16 + 3*k], v1 = xr[17 + 3*k], v2 = xr[18 + 3*k];
    #pragma unroll
    for (int a = 0; a < 3; a++)
      c[16 + 3*k + a] = R[a] * v0 + R[3 + a] * v1 + R[6 + a] * v2;  // R^T v
  }
  #pragma unroll
  for (int a = 0; a < 3; a++) c[64 + a] = pos[n * 3 + a];
  float sq = 0.f;
  #pragma unroll
  for (int d = 0; d < 67; d++) sq += c[d] * c[d];
  __attribute__((aligned(16))) unsigned short row[KROW];
  #pragma unroll
  for (int d = 0; d < 67; d++) row[d] = f2bf_rne(c[d]);
  #pragma unroll
  for (int d = 67; d < KROW; d++) row[d] = 0;
  uint4* dst = (uint4*)(kfB + (size_t)n * KROW);
  const uint4* s4 = (const uint4*)row;
  #pragma unroll
  for (int i = 0; i < 13; i++) dst[i] = s4[i];
  normB[n] = sq;
}

// ---------------------------------------------------------------------------
// k_wprep: pre-convert W1/W2 (f32, row-major [128][128]) to bf16 in the
// MFMA fragment layout a = ((k>>5)*128 + n)*32 + (k&31). Coalesced writes.
// ---------------------------------------------------------------------------
__global__ __launch_bounds__(256) void k_wprep(const float* __restrict__ W1,
        const float* __restrict__ W2, unsigned short* __restrict__ wb1,
        unsigned short* __restrict__ wb2){
  int a = blockIdx.x * 256 + threadIdx.x;      // 0..16383
  int kb = a >> 12, n = (a >> 5) & 127, kl = a & 31;
  int i = ((kb << 5) + kl) * 128 + n;
  wb1[a] = f2bf_rne(W1[i]);
  wb2[a] = f2bf_rne(W2[i]);
}

// ---------------------------------------------------------------------------
// col_compact32: EXACT top-32 (full 32-bit packed) of one column, cn<=144.
// Used only for the final per-column compact (merge expects exactly 32).
// ---------------------------------------------------------------------------
__device__ __forceinline__ unsigned col_compact32(unsigned* buf,
    int col, int cn, int lane){
  unsigned e0 = (lane < cn) ? buf[lane * CSTR + col] : 0xFFFFFFFFu;
  unsigned e1 = (lane + 64 < cn) ? buf[(lane + 64) * CSTR + col] : 0xFFFFFFFFu;
  unsigned T = 0;
  #pragma unroll 1
  for (int b = 31; b >= 0; --b){
    unsigned cand = T | (1u << b);
    int c = __popcll(__ballot(e0 < cand)) + __popcll(__ballot(e1 < cand));
    if (c <= 31) T = cand;   // largest U with count(<U)<=31  ==> 32nd smallest
  }
  unsigned long long m0 = __ballot(e0 <= T);
  unsigned long long m1 = __ballot(e1 <= T);
  int b1 = __popcll(m0);
  unsigned long long ltm = (1ull << lane) - 1ull;
  if (e0 <= T) buf[__popcll(m0 & ltm) * CSTR + col] = e0;
  if (e1 <= T) buf[(b1 + __popcll(m1 & ltm)) * CSTR + col] = e1;
  return T;
}

// ---------------------------------------------------------------------------
// col_compact18: mid-scan compact at d2 granularity (bits 31..14 only).
// Keeps (e>>14) <= (T>>14): tie-inclusive SUPERSET of the exact top-32
// (T+2^14 > exact 32nd value), count kc in [32, 32+ties]. 18 ballot rounds
// instead of 32. Returns T | kc (T's low 14 bits are zero by construction).
// ---------------------------------------------------------------------------
__device__ __forceinline__ unsigned col_compact18(unsigned* buf,
    int col, int cn, int lane){
  unsigned e0 = (lane < cn) ? buf[lane * CSTR + col] : 0xFFFFFFFFu;
  unsigned e1 = (lane + 64 < cn) ? buf[(lane + 64) * CSTR + col] : 0xFFFFFFFFu;
  unsigned T = 0;
  #pragma unroll 1
  for (int b = 31; b >= 14; --b){
    unsigned cand = T | (1u << b);
    int c = __popcll(__ballot(e0 < cand)) + __popcll(__ballot(e1 < cand));
    if (c <= 31) T = cand;   // largest mult-of-2^14 with count(<T)<=31
  }
  unsigned th = T >> 14;
  unsigned long long m0 = __ballot((e0 >> 14) <= th);
  unsigned long long m1 = __ballot((e1 >> 14) <= th);
  int b1 = __popcll(m0);
  int kc = b1 + __popcll(m1);
  unsigned long long ltm = (1ull << lane) - 1ull;
  if ((e0 >> 14) <= th) buf[__popcll(m0 & ltm) * CSTR + col] = e0;
  if ((e1 >> 14) <= th) buf[(b1 + __popcll(m1 & ltm)) * CSTR + col] = e1;
  return T | (unsigned)kc;
}

// ---------------------------------------------------------------------------
// k_knn: R3 scan structure, epilogue split out (R12), 18-round mid-scan
// compact (R13). Barrier-free wave-autonomous scan, 256 blocks x 1024 thr
// (16 waves). Wave (wq,kq): 16 queries x 4096 keys. Keys direct from global
// (L2-resident). Counts in quad-uniform registers; shared monotone tau via
// atomicMin, refreshed every 4 groups. Writes top-32 candidate indices
// (u16) per query to mgG.
// ---------------------------------------------------------------------------
__global__ __launch_bounds__(1024, 4) void k_knn(
    const unsigned short* __restrict__ kfB, const float* __restrict__ normB,
    unsigned short* __restrict__ mgG){
  __shared__ __attribute__((aligned(16))) char smem[KNN_SMEM];
  unsigned* buf = (unsigned*)smem;
  unsigned* tauG = (unsigned*)(smem + OFF_TAUG);

  int tid = threadIdx.x;
  int blk = blockIdx.x;
  int b = blk & 3;                 // batch; XCD (blk%8) serves one batch slice
  int qloc0 = (blk >> 2) << 6;     // query block within batch: 0..4032
  int bbase = b << 14;

  if (tid < 64) tauG[tid] = 0x7F7FC000u;   // huge float (not NaN)

  int lane = tid & 63;
  int wv = tid >> 6;               // 0..15
  int wq = wv >> 2;                // query sub-group 0..3
  int kq = wv & 3;                 // key quarter 0..3
  int l15 = lane & 15, quad = lane >> 4;
  int colB = (wq << 6) + kq;       // col = colB + quad*16 + r*4

  // A fragments: wave's 16 queries
  int qloc = qloc0 + (wq << 4);
  s16x8 af[3];
  {
    int nodeA = bbase + ((qloc + l15) << 2);
    const unsigned short* ap = kfB + (size_t)nodeA * KROW + quad * 8;
    af[0] = *(const s16x8*)(ap);
    af[1] = *(const s16x8*)(ap + 32);
    af[2] = *(const s16x8*)(ap + 64);
  }
  float qsq[4];
  #pragma unroll
  for (int r = 0; r < 4; r++)
    qsq[r] = normB[bbase + ((qloc + (quad << 2) + r) << 2)];

  float tauR[4] = {3.0e38f, 3.0e38f, 3.0e38f, 3.0e38f};
  int cntR[4];                     // quad-uniform per-column counts (registers)

  // key stream pointers (lane l15 -> key (kq*4096 + g*16 + l15))
  const unsigned short* kp = kfB + (size_t)(bbase + (kq << 12) + l15) * KROW + quad * 8;
  const float* np = normB + (bbase + (kq << 12) + l15);

  __syncthreads();   // tauG init visible

  s16x8 cK[4][3];
  float nK[4];
  #define LOADK(S) do { \
      cK[S][0] = *(const s16x8*)(kp); \
      cK[S][1] = *(const s16x8*)(kp + 32); \
      cK[S][2] = *(const s16x8*)(kp + 64); \
      nK[S] = *np; kp += 16 * KROW; np += 16; } while (0)

  auto comp = [&](const s16x8 bf[3], float ksqv, float d2v[4]){
    f32x4 acc = (f32x4){0.f, 0.f, 0.f, 0.f};
    acc = __builtin_amdgcn_mfma_f32_16x16x32_bf16(af[0], bf[0], acc, 0, 0, 0);
    acc = __builtin_amdgcn_mfma_f32_16x16x32_bf16(af[1], bf[1], acc, 0, 0, 0);
    acc = __builtin_amdgcn_mfma_f32_16x16x32_bf16(af[2], bf[2], acc, 0, 0, 0);
    #pragma unroll
    for (int r = 0; r < 4; r++)
      d2v[r] = fmaxf(qsq[r] + ksqv - 2.f * acc[r], 0.f);
  };

  auto seed = [&](const float d2v[4], int g){
    int kidx = (kq << 12) + (g << 4) + l15;
    #pragma unroll
    for (int r = 0; r < 4; r++){
      unsigned pk = ((__float_as_uint(d2v[r]) + 0x2000u) & 0xFFFFC000u) | (unsigned)kidx;
      buf[((g << 4) + l15) * CSTR + colB + (quad << 4) + (r << 2)] = pk;
    }
  };

  auto process = [&](const float d2v[4], int g){
    bool p[4];
    #pragma unroll
    for (int r = 0; r < 4; r++) p[r] = d2v[r] < tauR[r];
    if (__any(p[0] | p[1] | p[2] | p[3])){
      int kidx = (kq << 12) + (g << 4) + l15;
      #pragma unroll
      for (int r = 0; r < 4; r++){
        unsigned long long m = __ballot(p[r]);
        if (m){
          int lo = (int)((m >> (quad << 4)) & 0xFFFFull);
          if (lo){
            int colr = colB + (quad << 4) + (r << 2);
            int pre = __popc(lo & ((1 << l15) - 1));
            if (p[r]){
              unsigned pk = ((__float_as_uint(d2v[r]) + 0x2000u) & 0xFFFFC000u) | (unsigned)kidx;
              buf[(cntR[r] + pre) * CSTR + colr] = pk;
            }
            cntR[r] += __popc(lo);      // quad-uniform update, no atomics
          }
        }
      }
    }
  };

  // mid-scan compact (18-round, tie-inclusive, tracked count) + tau update
  auto check_compact = [&](int limit){
    #pragma unroll
    for (int r = 0; r < 4; r++){
      unsigned long long mr = __ballot(cntR[r] > limit);
      while (mr){
        int ldr = __ffsll((unsigned long long)mr) - 1;
        int qd = ldr >> 4;
        mr &= ~(0xFFFFull << (qd << 4));
        int col = colB + (qd << 4) + (r << 2);
        int cn = __shfl(cntR[r], qd << 4, 64);
        unsigned Tk = col_compact18(buf, col, cn, lane);
        if (quad == qd) cntR[r] = (int)(Tk & 0x3FFFu);
        if (lane == 0) atomicMin(&tauG[(wq << 4) + (qd << 2) + r], Tk & 0xFFFFC000u);
      }
    }
  };

  // ---- prologue: fill 4 slots, seed groups 0..3 unconditionally ----
  float d2v[4];
  LOADK(0); LOADK(1); LOADK(2); LOADK(3);    // g0..g3
  #pragma unroll
  for (int j = 0; j < 4; j++){
    comp(cK[j], nK[j], d2v);
    seed(d2v, j);
    LOADK(j);                                 // prefetch g4..g7
  }
  #pragma unroll
  for (int r = 0; r < 4; r++) cntR[r] = 64;

  // ---- main scan: 4 groups/iter, 4-deep register prefetch ----
  #pragma unroll 1
  for (int g = 4; g < 256; g += 4){
    #pragma unroll
    for (int j = 0; j < 4; j++){
      comp(cK[j], nK[j], d2v);
      LOADK(j);                               // prefetch g+4+j (tail overrun reads valid ws bytes)
      process(d2v, g + j);
    }
    check_compact(THRESH);
    uint4 tg = *(const uint4*)&tauG[(wq << 4) + (quad << 2)];
    tauR[0] = __uint_as_float(tg.x & 0xFFFFC000u);
    tauR[1] = __uint_as_float(tg.y & 0xFFFFC000u);
    tauR[2] = __uint_as_float(tg.z & 0xFFFFC000u);
    tauR[3] = __uint_as_float(tg.w & 0xFFFFC000u);
  }

  // ---- final per-column EXACT top-32 (merge expects exactly 32 rows) ----
  {
    #pragma unroll
    for (int r = 0; r < 4; r++){
      unsigned long long mr = __ballot(cntR[r] > 32);
      while (mr){
        int ldr = __ffsll((unsigned long long)mr) - 1;
        int qd = ldr >> 4;
        mr &= ~(0xFFFFull << (qd << 4));
        int col = colB + (qd << 4) + (r << 2);
        int cn = __shfl(cntR[r], qd << 4, 64);
        col_compact32(buf, col, cn, lane);
        if (quad == qd) cntR[r] = 32;
      }
    }
  }
  __syncthreads();

  // ---- per-query merge of 4 columns (4x32 = 128 fixed) -> top-32 indices
  //      written straight to global mgG (u16 node index within batch) ----
  #pragma unroll 1
  for (int s = 0; s < 4; s++){
    int q = (wv << 2) + s;           // 0..63
    int qid = (b << 12) + qloc0 + q;
    unsigned e0 = buf[(lane & 31) * CSTR + (q << 2) + (lane >> 5)];
    unsigned e1 = buf[(lane & 31) * CSTR + (q << 2) + 2 + (lane >> 5)];
    unsigned T = 0;
    #pragma unroll 1
    for (int bb = 31; bb >= 0; --bb){
      unsigned cand = T | (1u << bb);
      int c = __popcll(__ballot(e0 < cand)) + __popcll(__ballot(e1 < cand));
      if (c <= 31) T = cand;
    }
    unsigned long long m0 = __ballot(e0 <= T);
    unsigned long long m1 = __ballot(e1 <= T);
    int b1 = __popcll(m0);
    unsigned long long ltm = (1ull << lane) - 1ull;
    int p0 = __popcll(m0 & ltm);
    int p1 = b1 + __popcll(m1 & ltm);
    if ((e0 <= T) && (p0 < 32)) mgG[qid * 32 + p0] = (unsigned short)(e0 & 0x3FFFu);
    if ((e1 <= T) && (p1 < 32)) mgG[qid * 32 + p1] = (unsigned short)(e1 & 0x3FFFu);
  }
}

// ---------------------------------------------------------------------------
// k_mlp with FUSED rerank: 8 queries/block, 512 thr. Phase A (256 lanes):
// fp64 rerank of the 32 mgG candidates/query (1 per lane, qkf overlays xs
// region) + shfl rank-select; the top-20 SET (max over edges is order-
// invariant) lands directly in nbrL -- no nbr global round-trip, no separate
// kernel. Then gather / h-build / 2x MFMA layers / max, as before. Weight
// fragments straight from pre-transposed wb1/wb2 (L2) into registers.
// ---------------------------------------------------------------------------
#define M_X   0         // qkf f64[8][68]=4352 ; xs f32[160][68]=43520 ; a1B bf16 40960
#define M_H   43520     // hB bf16[4][160][32] = 40960
#define M_B1  84480     // b1 f32[128]
#define M_B2  84992     // b2 f32[128]
#define M_NBR 85504     // nbrL i32[160] = 640
#define M_XD  86144     // xdL f32[8][64] = 2048
#define M_LF  88192     // lfL f32[8][9] = 288
#define M_SZ  88512

__global__ __launch_bounds__(512) void k_mlp(const float* __restrict__ x,
    const float* __restrict__ pos, const float* __restrict__ lfr,
    const unsigned short* __restrict__ mgG,
    const unsigned short* __restrict__ wb1, const unsigned short* __restrict__ wb2,
    const float* __restrict__ b1, const float* __restrict__ b2,
    float* __restrict__ out){
  __shared__ __attribute__((aligned(16))) char smem[M_SZ];
  double* qkf = (double*)(smem + M_X);                   // phase A (dead before xs)
  float* xsF = (float*)(smem + M_X);
  unsigned short* a1B = (unsigned short*)(smem + M_X);   // overlays xs (dead)
  unsigned short* hB = (unsigned short*)(smem + M_H);
  float* b1L = (float*)(smem + M_B1);
  float* b2L = (float*)(smem + M_B2);
  int*   nbrL = (int*)(smem + M_NBR);
  float* xdL  = (float*)(smem + M_XD);
  float* lfL  = (float*)(smem + M_LF);

  int tid = threadIdx.x;
  int qid0 = blockIdx.x * 8;
  int lane = tid & 63, wv = tid >> 6;
  int l15 = lane & 15, quad = lane >> 4;

  // ---- weight fragments: straight from global (L2) into registers ----
  s16x8 wf1[4], wf2[4];
  #pragma unroll
  for (int ks = 0; ks < 4; ks++){
    int a = (ks * 128 + (wv << 4) + l15) * 32 + (quad << 3);
    wf1[ks] = *(const s16x8*)(wb1 + a);
    wf2[ks] = *(const s16x8*)(wb2 + a);
  }

  // ---- init loads + qkf build (phase A prep) ----
  {
    int q = tid >> 6, d = tid & 63;
    int qid = qid0 + q;
    int node = ((qid >> 12) << 14) + ((qid & 4095) << 2);
    xdL[q * 64 + d] = x[node * 64 + d];
  }
  if (tid < 72){
    int q = tid / 9, j = tid - 9 * q;
    int qid = qid0 + q;
    int node = ((qid >> 12) << 14) + ((qid & 4095) << 2);
    lfL[q * 9 + j] = lfr[node * 9 + j];
  }
  if (tid < 128){ b1L[tid] = b1[tid]; b2L[tid] = b2[tid]; }
  if (tid < 256){
    int ql = tid >> 5, j = tid & 31;
    int qid = qid0 + ql;
    int node_q = ((qid >> 12) << 14) + ((qid & 4095) << 2);
    const float* xr = x + node_q * 64;
    for (int dd = j; dd < 67; dd += 32){
      double val;
      if (dd < 16) val = (double)xr[dd];
      else if (dd < 64){
        int r = dd - 16; int k = r / 3; int a = r - 3 * k;
        val = (double)lfr[node_q*9 + a]     * (double)xr[16 + 3*k]
            + (double)lfr[node_q*9 + 3 + a] * (double)xr[17 + 3*k]
            + (double)lfr[node_q*9 + 6 + a] * (double)xr[18 + 3*k];
      } else val = (double)pos[node_q*3 + (dd - 64)];
      qkf[ql * 68 + dd] = val;
    }
  }
  __syncthreads();

  // ---- phase A: fp64 rerank (1 candidate per lane) -> top-20 set in nbrL ----
  if (tid < 256){
    int ql = tid >> 5, j = tid & 31;
    int qid = qid0 + ql;
    int bbase = (qid >> 12) << 14;
    int idx = (int)mgG[(size_t)qid * 32 + j];
    int node = bbase + idx;
    const float* xr = x + node * 64;
    double R[9];
    #pragma unroll
    for (int t = 0; t < 9; t++) R[t] = (double)lfr[node * 9 + t];
    double d2 = 0.0;
    #pragma unroll
    for (int dd = 0; dd < 16; dd++){ double t = (double)xr[dd] - qkf[ql*68 + dd]; d2 += t * t; }
    #pragma unroll
    for (int k = 0; k < 16; k++){
      double v0 = xr[16 + 3*k], v1 = xr[17 + 3*k], v2 = xr[18 + 3*k];
      #pragma unroll
      for (int a = 0; a < 3; a++){
        double val = R[a] * v0 + R[3 + a] * v1 + R[6 + a] * v2;
        double t = val - qkf[ql*68 + 16 + 3*k + a]; d2 += t * t;
      }
    }
    #pragma unroll
    for (int a = 0; a < 3; a++){ double t = (double)pos[node*3 + a] - qkf[ql*68 + 64 + a]; d2 += t * t; }

    // rank within the query's 32 lanes: (d2, j) lexicographic == ref sort order
    int base = (tid & 32) ? 32 : 0;    // half-wave base within the wave
    int rank = 0;
    #pragma unroll 1
    for (int j2 = 0; j2 < 32; j2++){
      double o = __shfl(d2, base + j2, 64);
      rank += (o < d2) || ((o == d2) && (j2 < j));
    }
    if (rank < KNN) nbrL[ql * KNN + rank] = node;
  }
  __syncthreads();   // nbrL complete; qkf dead (xs may now be written)

  // ---- gather x_src into xs (160 rows x 64 f32, stride 68) ----
  {
    int f4 = tid & 15;
    #pragma unroll
    for (int p = 0; p < 5; p++){
      int e = (tid >> 4) + (p << 5);
      float4 v = *(const float4*)&x[(size_t)nbrL[e] * 64 + (f4 << 2)];
      *(float4*)&xsF[e * 68 + (f4 << 2)] = v;
    }
  }
  __syncthreads();

  // ---- build h bf16 into hB [d>>5][e][d&31] ----
  {
    int d = tid & 127, eo = tid >> 7;   // eo 0..3
    int cls, kk = 0, aa = 0;
    if (d < 64) cls = 0;
    else { int dd = d - 64;
      if (dd < 16) cls = 1;
      else { cls = 2; int r = dd - 16; kk = (r * 21846) >> 16; aa = r - 3 * kk; } }
    int hoff = ((d >> 5) * 160) * 32 + (d & 31);
    #pragma unroll 4
    for (int p = 0; p < 40; p++){
      int e = eo + (p << 2);
      int q = (e * 3277) >> 16;       // e/20 for e<160
      float v;
      if (cls == 0) v = xdL[q * 64 + d];
      else if (cls == 1) v = xsF[e * 68 + (d - 64)] - xdL[q * 64 + (d - 64)];
      else {
        int base = 16 + 3 * kk;
        float u0 = xsF[e * 68 + base]     - xdL[q * 64 + base];
        float u1 = xsF[e * 68 + base + 1] - xdL[q * 64 + base + 1];
        float u2 = xsF[e * 68 + base + 2] - xdL[q * 64 + base + 2];
        v = lfL[q * 9 + aa * 3] * u0 + lfL[q * 9 + aa * 3 + 1] * u1 + lfL[q * 9 + aa * 3 + 2] * u2;
      }
      hB[hoff + e * 32] = f2bf_rne(v);
    }
  }
  __syncthreads();   // hB done; xs dead (a1B may now be written)

  // ---- layer 1: a1 = relu(h @ W1 + b1) ----
  {
    float b1v = b1L[(wv << 4) + l15];
    int colhi = wv >> 1, collo = ((wv & 1) << 4) + l15;
    #pragma unroll
    for (int mt = 0; mt < 10; mt++){
      f32x4 acc = (f32x4){0.f, 0.f, 0.f, 0.f};
      #pragma unroll
      for (int ks = 0; ks < 4; ks++){
        s16x8 af = *(const s16x8*)(hB + ((ks * 160 + (mt << 4) + l15) * 32 + (quad << 3)));
        acc = __builtin_amdgcn_mfma_f32_16x16x32_bf16(af, wf1[ks], acc, 0, 0, 0);
      }
      #pragma unroll
      for (int r = 0; r < 4; r++){
        float v = fmaxf(acc[r] + b1v, 0.f);
        int row = (mt << 4) + (quad << 2) + r;
        a1B[(colhi * 160 + row) * 32 + collo] = f2bf_rne(v);
      }
    }
  }
  __syncthreads();   // a1 complete

  // ---- layer 2 + max over edges (registers only) ----
  {
    float mxv[8];
    #pragma unroll
    for (int q = 0; q < 8; q++) mxv[q] = -3.0e38f;
    const int QA[10]  = {0,0,1,2,3,4,4,5,6,7};
    const int CUT[10] = {16,4,8,12,16,16,4,8,12,16};
    #pragma unroll
    for (int mt = 0; mt < 10; mt++){
      f32x4 acc = (f32x4){0.f, 0.f, 0.f, 0.f};
      #pragma unroll
      for (int ks = 0; ks < 4; ks++){
        s16x8 af = *(const s16x8*)(a1B + ((ks * 160 + (mt << 4) + l15) * 32 + (quad << 3)));
        acc = __builtin_amdgcn_mfma_f32_16x16x32_bf16(af, wf2[ks], acc, 0, 0, 0);
      }
      int qa = QA[mt], cut = CUT[mt];
      if (cut >= 16){
        #pragma unroll
        for (int r = 0; r < 4; r++) mxv[qa] = fmaxf(mxv[qa], acc[r]);
      } else {
        #pragma unroll
        for (int r = 0; r < 4; r++){
          int lr = (quad << 2) + r;
          bool toA = lr < cut;
          mxv[qa]     = fmaxf(mxv[qa],     toA ? acc[r] : -3.0e38f);
          mxv[qa + 1] = fmaxf(mxv[qa + 1], toA ? -3.0e38f : acc[r]);
        }
      }
    }
    // combine across quads (rows) -- all lanes end with full per-col max
    #pragma unroll
    for (int q = 0; q < 8; q++){
      float v = mxv[q];
      v = fmaxf(v, __shfl_xor(v, 16, 64));
      v = fmaxf(v, __shfl_xor(v, 32, 64));
      mxv[q] = v;
    }
    if (quad == 0){
      int col = (wv << 4) + l15;
      float b2v = b2L[col];
      #pragma unroll
      for (int q = 0; q < 8; q++)
        out[(size_t)(qid0 + q) * 128 + col] = mxv[q] + b2v;
    }
  }
}

// ---------------------------------------------------------------------------
// k_tail: pos[idx], batch[idx], lframes[idx] as fp32 at flat offsets.
// ---------------------------------------------------------------------------
__global__ __launch_bounds__(256) void k_tail(const float* __restrict__ pos,
    const float* __restrict__ lfr, float* __restrict__ out){
  int q = blockIdx.x * 256 + threadIdx.x;   // 0..16383
  int b = q >> 12;
  int node = (b << 14) + ((q & 4095) << 2);
  float* o_pos = out + 2097152;    // 16384*128
  float* o_bat = out + 2146304;    // + 16384*3
  float* o_lf  = out + 2162688;    // + 16384
  #pragma unroll
  for (int j = 0; j < 3; j++) o_pos[q * 3 + j] = pos[node * 3 + j];
  o_bat[q] = (float)b;
  #pragma unroll
  for (int j = 0; j < 9; j++) o_lf[q * 9 + j] = lfr[node * 9 + j];
}

extern "C" void kernel_launch(void* const* d_in, const int* in_sizes, int n_in,
                              void* d_out, int out_size, void* d_ws, size_t ws_size,
                              hipStream_t stream){
  const float* x   = (const float*)d_in[0];
  const float* pos = (const float*)d_in[1];
  const float* lfr = (const float*)d_in[2];
  // d_in[3] = batch (recomputed analytically)
  const float* W1  = (const float*)d_in[4];
  const float* b1  = (const float*)d_in[5];
  const float* W2  = (const float*)d_in[6];
  const float* b2  = (const float*)d_in[7];

  unsigned short* kfB = (unsigned short*)d_ws;
  float* normB = (float*)((char*)d_ws + WS_NORM);
  unsigned short* wb1 = (unsigned short*)((char*)d_ws + WS_WT1);
  unsigned short* wb2 = (unsigned short*)((char*)d_ws + WS_WT2);
  unsigned short* mgG = (unsigned short*)((char*)d_ws + WS_MG);
  float* out = (float*)d_out;

  hipLaunchKernelGGL(k_prep,   dim3(256),  dim3(256),  0, stream, x, pos, lfr, kfB, normB);
  hipLaunchKernelGGL(k_wprep,  dim3(64),   dim3(256),  0, stream, W1, W2, wb1, wb2);
  hipLaunchKernelGGL(k_knn,    dim3(256),  dim3(1024), 0, stream, kfB, normB, mgG);
  hipLaunchKernelGGL(k_mlp,    dim3(2048), dim3(512),  0, stream, x, pos, lfr, mgG, wb1, wb2, b1, b2, out);
  hipLaunchKernelGGL(k_tail,   dim3(64),   dim3(256),  0, stream, pos, lfr, out);
}

// Round 15
// 503.602 us; speedup vs baseline: 1.0642x; 1.0642x over previous
//
#include <hip/hip_runtime.h>
#include <hip/hip_bf16.h>

// Problem constants
#define NTOT 65536      // B*N
#define KNN  20
#define KROW 104        // bf16 kf row stride (67 dims + pad)

typedef __attribute__((ext_vector_type(4))) float f32x4;
typedef __attribute__((ext_vector_type(8))) short s16x8;

// ws layout (bytes): kfB bf16[65536][104] | normB f32[65536] | (unused) |
//                    wb1 bf16[16384] | wb2 bf16[16384] | mg u16[16384*32]
#define WS_NORM 13631488
#define WS_WT1  15204352
#define WS_WT2  15237120
#define WS_MG   15269888    // 1 MB; ws end = 16318464 < 16 MiB

// ---- k_knn LDS map (bytes) ----
#define ROWS 144
#define CSTR 257
#define OFF_TAUG 149056     // unsigned tauG[64]
#define KNN_SMEM 149312
#define THRESH 64           // compact a column when cnt > THRESH (max cn <= 144)

__device__ __forceinline__ unsigned short f2bf_rne(float v){
  unsigned u = __float_as_uint(v);
  return (unsigned short)((u + 0x7FFFu + ((u >> 16) & 1u)) >> 16);
}

// ---------------------------------------------------------------------------
// k_prep: kf = [s(16), R^T v(48), pos(3)] -> bf16 rows (stride 104) + f32 norm
// ---------------------------------------------------------------------------
__global__ __launch_bounds__(256) void k_prep(const float* __restrict__ x,
        const float* __restrict__ pos, const float* __restrict__ lfr,
        unsigned short* __restrict__ kfB, float* __restrict__ normB){
  int n = blockIdx.x * 256 + threadIdx.x;
  const float* xr = x + n * 64;
  float R[9];
  #pragma unroll
  for (int j = 0; j < 9; j++) R[j] = lfr[n * 9 + j];
  float c[67];
  #pragma unroll
  for (int i = 0; i < 16; i++) c[i] = xr[i];
  #pragma unroll
  for (int k = 0; k < 16; k++){
    float v0 = xr[16 + 3*k], v1 = xr[17 + 3*k], v2 = xr[18 + 3*k];
    #pragma unroll
    for (int a = 0; a < 3; a++)
      c[16 + 3*k + a] = R[a] * v0 + R[3 + a] * v1 + R[6 + a] * v2;  // R^T v
  }
  #pragma unroll
  for (int a = 0; a < 3; a++) c[64 + a] = pos[n * 3 + a];
  float sq = 0.f;
  #pragma unroll
  for (int d = 0; d < 67; d++) sq += c[d] * c[d];
  __attribute__((aligned(16))) unsigned short row[KROW];
  #pragma unroll
  for (int d = 0; d < 67; d++) row[d] = f2bf_rne(c[d]);
  #pragma unroll
  for (int d = 67; d < KROW; d++) row[d] = 0;
  uint4* dst = (uint4*)(kfB + (size_t)n * KROW);
  const uint4* s4 = (const uint4*)row;
  #pragma unroll
  for (int i = 0; i < 13; i++) dst[i] = s4[i];
  normB[n] = sq;
}

// ---------------------------------------------------------------------------
// k_wprep: pre-convert W1/W2 (f32, row-major [128][128]) to bf16 in the
// MFMA fragment layout a = ((k>>5)*128 + n)*32 + (k&31). Coalesced writes.
// ---------------------------------------------------------------------------
__global__ __launch_bounds__(256) void k_wprep(const float* __restrict__ W1,
        const float* __restrict__ W2, unsigned short* __restrict__ wb1,
        unsigned short* __restrict__ wb2){
  int a = blockIdx.x * 256 + threadIdx.x;      // 0..16383
  int kb = a >> 12, n = (a >> 5) & 127, kl = a & 31;
  int i = ((kb << 5) + kl) * 128 + n;
  wb1[a] = f2bf_rne(W1[i]);
  wb2[a] = f2bf_rne(W2[i]);
}

// ---------------------------------------------------------------------------
// col_compact32: EXACT top-32 (full 32-bit packed) of one column, cn<=144.
// ---------------------------------------------------------------------------
__device__ __forceinline__ unsigned col_compact32(unsigned* buf,
    int col, int cn, int lane){
  unsigned e0 = (lane < cn) ? buf[lane * CSTR + col] : 0xFFFFFFFFu;
  unsigned e1 = (lane + 64 < cn) ? buf[(lane + 64) * CSTR + col] : 0xFFFFFFFFu;
  unsigned T = 0;
  #pragma unroll 1
  for (int b = 31; b >= 0; --b){
    unsigned cand = T | (1u << b);
    int c = __popcll(__ballot(e0 < cand)) + __popcll(__ballot(e1 < cand));
    if (c <= 31) T = cand;   // largest U with count(<U)<=31  ==> 32nd smallest
  }
  unsigned long long m0 = __ballot(e0 <= T);
  unsigned long long m1 = __ballot(e1 <= T);
  int b1 = __popcll(m0);
  unsigned long long ltm = (1ull << lane) - 1ull;
  if (e0 <= T) buf[__popcll(m0 & ltm) * CSTR + col] = e0;
  if (e1 <= T) buf[(b1 + __popcll(m1 & ltm)) * CSTR + col] = e1;
  return T;
}

// ---------------------------------------------------------------------------
// col_compact18: mid-scan compact at d2 granularity (bits 31..14 only).
// Tie-inclusive SUPERSET of exact top-32; returns T | kc.
// ---------------------------------------------------------------------------
__device__ __forceinline__ unsigned col_compact18(unsigned* buf,
    int col, int cn, int lane){
  unsigned e0 = (lane < cn) ? buf[lane * CSTR + col] : 0xFFFFFFFFu;
  unsigned e1 = (lane + 64 < cn) ? buf[(lane + 64) * CSTR + col] : 0xFFFFFFFFu;
  unsigned T = 0;
  #pragma unroll 1
  for (int b = 31; b >= 14; --b){
    unsigned cand = T | (1u << b);
    int c = __popcll(__ballot(e0 < cand)) + __popcll(__ballot(e1 < cand));
    if (c <= 31) T = cand;   // largest mult-of-2^14 with count(<T)<=31
  }
  unsigned th = T >> 14;
  unsigned long long m0 = __ballot((e0 >> 14) <= th);
  unsigned long long m1 = __ballot((e1 >> 14) <= th);
  int b1 = __popcll(m0);
  int kc = b1 + __popcll(m1);
  unsigned long long ltm = (1ull << lane) - 1ull;
  if ((e0 >> 14) <= th) buf[__popcll(m0 & ltm) * CSTR + col] = e0;
  if ((e1 >> 14) <= th) buf[(b1 + __popcll(m1 & ltm)) * CSTR + col] = e1;
  return T | (unsigned)kc;
}

// ---------------------------------------------------------------------------
// k_knn: R3 scan structure, epilogue split out, 18-round mid-scan compact.
// Barrier-free wave-autonomous scan, 256 blocks x 1024 thr (16 waves).
// Writes top-32 candidate indices (u16) per query to mgG.
// ---------------------------------------------------------------------------
__global__ __launch_bounds__(1024, 4) void k_knn(
    const unsigned short* __restrict__ kfB, const float* __restrict__ normB,
    unsigned short* __restrict__ mgG){
  __shared__ __attribute__((aligned(16))) char smem[KNN_SMEM];
  unsigned* buf = (unsigned*)smem;
  unsigned* tauG = (unsigned*)(smem + OFF_TAUG);

  int tid = threadIdx.x;
  int blk = blockIdx.x;
  int b = blk & 3;                 // batch; XCD (blk%8) serves one batch slice
  int qloc0 = (blk >> 2) << 6;     // query block within batch: 0..4032
  int bbase = b << 14;

  if (tid < 64) tauG[tid] = 0x7F7FC000u;   // huge float (not NaN)

  int lane = tid & 63;
  int wv = tid >> 6;               // 0..15
  int wq = wv >> 2;                // query sub-group 0..3
  int kq = wv & 3;                 // key quarter 0..3
  int l15 = lane & 15, quad = lane >> 4;
  int colB = (wq << 6) + kq;       // col = colB + quad*16 + r*4

  // A fragments: wave's 16 queries
  int qloc = qloc0 + (wq << 4);
  s16x8 af[3];
  {
    int nodeA = bbase + ((qloc + l15) << 2);
    const unsigned short* ap = kfB + (size_t)nodeA * KROW + quad * 8;
    af[0] = *(const s16x8*)(ap);
    af[1] = *(const s16x8*)(ap + 32);
    af[2] = *(const s16x8*)(ap + 64);
  }
  float qsq[4];
  #pragma unroll
  for (int r = 0; r < 4; r++)
    qsq[r] = normB[bbase + ((qloc + (quad << 2) + r) << 2)];

  float tauR[4] = {3.0e38f, 3.0e38f, 3.0e38f, 3.0e38f};
  int cntR[4];                     // quad-uniform per-column counts (registers)

  // key stream pointers (lane l15 -> key (kq*4096 + g*16 + l15))
  const unsigned short* kp = kfB + (size_t)(bbase + (kq << 12) + l15) * KROW + quad * 8;
  const float* np = normB + (bbase + (kq << 12) + l15);

  __syncthreads();   // tauG init visible

  s16x8 cK[4][3];
  float nK[4];
  #define LOADK(S) do { \
      cK[S][0] = *(const s16x8*)(kp); \
      cK[S][1] = *(const s16x8*)(kp + 32); \
      cK[S][2] = *(const s16x8*)(kp + 64); \
      nK[S] = *np; kp += 16 * KROW; np += 16; } while (0)

  auto comp = [&](const s16x8 bf[3], float ksqv, float d2v[4]){
    f32x4 acc = (f32x4){0.f, 0.f, 0.f, 0.f};
    acc = __builtin_amdgcn_mfma_f32_16x16x32_bf16(af[0], bf[0], acc, 0, 0, 0);
    acc = __builtin_amdgcn_mfma_f32_16x16x32_bf16(af[1], bf[1], acc, 0, 0, 0);
    acc = __builtin_amdgcn_mfma_f32_16x16x32_bf16(af[2], bf[2], acc, 0, 0, 0);
    #pragma unroll
    for (int r = 0; r < 4; r++)
      d2v[r] = fmaxf(qsq[r] + ksqv - 2.f * acc[r], 0.f);
  };

  auto seed = [&](const float d2v[4], int g){
    int kidx = (kq << 12) + (g << 4) + l15;
    #pragma unroll
    for (int r = 0; r < 4; r++){
      unsigned pk = ((__float_as_uint(d2v[r]) + 0x2000u) & 0xFFFFC000u) | (unsigned)kidx;
      buf[((g << 4) + l15) * CSTR + colB + (quad << 4) + (r << 2)] = pk;
    }
  };

  auto process = [&](const float d2v[4], int g){
    bool p[4];
    #pragma unroll
    for (int r = 0; r < 4; r++) p[r] = d2v[r] < tauR[r];
    if (__any(p[0] | p[1] | p[2] | p[3])){
      int kidx = (kq << 12) + (g << 4) + l15;
      #pragma unroll
      for (int r = 0; r < 4; r++){
        unsigned long long m = __ballot(p[r]);
        if (m){
          int lo = (int)((m >> (quad << 4)) & 0xFFFFull);
          if (lo){
            int colr = colB + (quad << 4) + (r << 2);
            int pre = __popc(lo & ((1 << l15) - 1));
            if (p[r]){
              unsigned pk = ((__float_as_uint(d2v[r]) + 0x2000u) & 0xFFFFC000u) | (unsigned)kidx;
              buf[(cntR[r] + pre) * CSTR + colr] = pk;
            }
            cntR[r] += __popc(lo);      // quad-uniform update, no atomics
          }
        }
      }
    }
  };

  // mid-scan compact (18-round, tie-inclusive, tracked count) + tau update
  auto check_compact = [&](int limit){
    #pragma unroll
    for (int r = 0; r < 4; r++){
      unsigned long long mr = __ballot(cntR[r] > limit);
      while (mr){
        int ldr = __ffsll((unsigned long long)mr) - 1;
        int qd = ldr >> 4;
        mr &= ~(0xFFFFull << (qd << 4));
        int col = colB + (qd << 4) + (r << 2);
        int cn = __shfl(cntR[r], qd << 4, 64);
        unsigned Tk = col_compact18(buf, col, cn, lane);
        if (quad == qd) cntR[r] = (int)(Tk & 0x3FFFu);
        if (lane == 0) atomicMin(&tauG[(wq << 4) + (qd << 2) + r], Tk & 0xFFFFC000u);
      }
    }
  };

  // ---- prologue: fill 4 slots, seed groups 0..3 unconditionally ----
  float d2v[4];
  LOADK(0); LOADK(1); LOADK(2); LOADK(3);    // g0..g3
  #pragma unroll
  for (int j = 0; j < 4; j++){
    comp(cK[j], nK[j], d2v);
    seed(d2v, j);
    LOADK(j);                                 // prefetch g4..g7
  }
  #pragma unroll
  for (int r = 0; r < 4; r++) cntR[r] = 64;

  // ---- main scan: 4 groups/iter, 4-deep register prefetch ----
  #pragma unroll 1
  for (int g = 4; g < 256; g += 4){
    #pragma unroll
    for (int j = 0; j < 4; j++){
      comp(cK[j], nK[j], d2v);
      LOADK(j);                               // prefetch g+4+j (tail overrun reads valid ws bytes)
      process(d2v, g + j);
    }
    check_compact(THRESH);
    uint4 tg = *(const uint4*)&tauG[(wq << 4) + (quad << 2)];
    tauR[0] = __uint_as_float(tg.x & 0xFFFFC000u);
    tauR[1] = __uint_as_float(tg.y & 0xFFFFC000u);
    tauR[2] = __uint_as_float(tg.z & 0xFFFFC000u);
    tauR[3] = __uint_as_float(tg.w & 0xFFFFC000u);
  }

  // ---- final per-column EXACT top-32 (merge expects exactly 32 rows) ----
  {
    #pragma unroll
    for (int r = 0; r < 4; r++){
      unsigned long long mr = __ballot(cntR[r] > 32);
      while (mr){
        int ldr = __ffsll((unsigned long long)mr) - 1;
        int qd = ldr >> 4;
        mr &= ~(0xFFFFull << (qd << 4));
        int col = colB + (qd << 4) + (r << 2);
        int cn = __shfl(cntR[r], qd << 4, 64);
        col_compact32(buf, col, cn, lane);
        if (quad == qd) cntR[r] = 32;
      }
    }
  }
  __syncthreads();

  // ---- per-query merge of 4 columns (4x32 = 128 fixed) -> top-32 indices ----
  #pragma unroll 1
  for (int s = 0; s < 4; s++){
    int q = (wv << 2) + s;           // 0..63
    int qid = (b << 12) + qloc0 + q;
    unsigned e0 = buf[(lane & 31) * CSTR + (q << 2) + (lane >> 5)];
    unsigned e1 = buf[(lane & 31) * CSTR + (q << 2) + 2 + (lane >> 5)];
    unsigned T = 0;
    #pragma unroll 1
    for (int bb = 31; bb >= 0; --bb){
      unsigned cand = T | (1u << bb);
      int c = __popcll(__ballot(e0 < cand)) + __popcll(__ballot(e1 < cand));
      if (c <= 31) T = cand;
    }
    unsigned long long m0 = __ballot(e0 <= T);
    unsigned long long m1 = __ballot(e1 <= T);
    int b1 = __popcll(m0);
    unsigned long long ltm = (1ull << lane) - 1ull;
    int p0 = __popcll(m0 & ltm);
    int p1 = b1 + __popcll(m1 & ltm);
    if ((e0 <= T) && (p0 < 32)) mgG[qid * 32 + p0] = (unsigned short)(e0 & 0x3FFFu);
    if ((e1 <= T) && (p1 < 32)) mgG[qid * 32 + p1] = (unsigned short)(e1 & 0x3FFFu);
  }
}

// ---------------------------------------------------------------------------
// k_mlp (fused rerank, SMALL blocks): 4 queries/block = 80 edge-rows
// (5 m-tiles), 256 thr (4 waves; wave owns 32 output cols = 2 fragments).
// LDS 44.8KB -> 3 blocks/CU: three independent blocks overlap each other's
// phase latencies (the R14 fusion was neutral because 88.5KB forced
// 1 block/CU). Same math, same summation order, same tie-breaks.
// ---------------------------------------------------------------------------
#define M_X   0         // qkf f64[4][68]=2176 ; xs f32[80][68]=21760 ; a1B bf16[4][80][32]=20480
#define M_H   21760     // hB bf16[4][80][32] = 20480
#define M_B1  42240     // b1 f32[128]
#define M_B2  42752     // b2 f32[128]
#define M_NBR 43264     // nbrL i32[80] = 320
#define M_XD  43584     // xdL f32[4][64] = 1024
#define M_LF  44608     // lfL f32[4][9] = 144
#define M_SZ  44752

__global__ __launch_bounds__(256) void k_mlp(const float* __restrict__ x,
    const float* __restrict__ pos, const float* __restrict__ lfr,
    const unsigned short* __restrict__ mgG,
    const unsigned short* __restrict__ wb1, const unsigned short* __restrict__ wb2,
    const float* __restrict__ b1, const float* __restrict__ b2,
    float* __restrict__ out){
  __shared__ __attribute__((aligned(16))) char smem[M_SZ];
  double* qkf = (double*)(smem + M_X);                   // phase A (dead before xs)
  float* xsF = (float*)(smem + M_X);
  unsigned short* a1B = (unsigned short*)(smem + M_X);   // overlays xs (dead)
  unsigned short* hB = (unsigned short*)(smem + M_H);
  float* b1L = (float*)(smem + M_B1);
  float* b2L = (float*)(smem + M_B2);
  int*   nbrL = (int*)(smem + M_NBR);
  float* xdL  = (float*)(smem + M_XD);
  float* lfL  = (float*)(smem + M_LF);

  int tid = threadIdx.x;
  int qid0 = blockIdx.x * 4;
  int lane = tid & 63, wv = tid >> 6;     // wv 0..3
  int l15 = lane & 15, quad = lane >> 4;

  // ---- weight fragments: straight from global (L2) into registers.
  //      wave wv owns output cols [wv*32, wv*32+32): 2 fragments per layer.
  s16x8 wf1[2][4], wf2[2][4];
  #pragma unroll
  for (int ct = 0; ct < 2; ct++)
    #pragma unroll
    for (int ks = 0; ks < 4; ks++){
      int a = (ks * 128 + (wv << 5) + (ct << 4) + l15) * 32 + (quad << 3);
      wf1[ct][ks] = *(const s16x8*)(wb1 + a);
      wf2[ct][ks] = *(const s16x8*)(wb2 + a);
    }

  // ---- init loads + qkf build (phase A prep) ----
  {
    int q = tid >> 6, d = tid & 63;       // 4 queries x 64 dims = 256 threads
    int qid = qid0 + q;
    int node = ((qid >> 12) << 14) + ((qid & 4095) << 2);
    xdL[q * 64 + d] = x[node * 64 + d];
  }
  if (tid < 36){
    int q = tid / 9, j = tid - 9 * q;
    int qid = qid0 + q;
    int node = ((qid >> 12) << 14) + ((qid & 4095) << 2);
    lfL[q * 9 + j] = lfr[node * 9 + j];
  }
  if (tid < 128){ b1L[tid] = b1[tid]; b2L[tid] = b2[tid]; }
  if (tid < 128){
    int ql = tid >> 5, j = tid & 31;
    int qid = qid0 + ql;
    int node_q = ((qid >> 12) << 14) + ((qid & 4095) << 2);
    const float* xr = x + node_q * 64;
    for (int dd = j; dd < 67; dd += 32){
      double val;
      if (dd < 16) val = (double)xr[dd];
      else if (dd < 64){
        int r = dd - 16; int k = r / 3; int a = r - 3 * k;
        val = (double)lfr[node_q*9 + a]     * (double)xr[16 + 3*k]
            + (double)lfr[node_q*9 + 3 + a] * (double)xr[17 + 3*k]
            + (double)lfr[node_q*9 + 6 + a] * (double)xr[18 + 3*k];
      } else val = (double)pos[node_q*3 + (dd - 64)];
      qkf[ql * 68 + dd] = val;
    }
  }
  __syncthreads();

  // ---- phase A: fp64 rerank (1 candidate per lane) -> top-20 set in nbrL ----
  if (tid < 128){
    int ql = tid >> 5, j = tid & 31;
    int qid = qid0 + ql;
    int bbase = (qid >> 12) << 14;
    int idx = (int)mgG[(size_t)qid * 32 + j];
    int node = bbase + idx;
    const float* xr = x + node * 64;
    double R[9];
    #pragma unroll
    for (int t = 0; t < 9; t++) R[t] = (double)lfr[node * 9 + t];
    double d2 = 0.0;
    #pragma unroll
    for (int dd = 0; dd < 16; dd++){ double t = (double)xr[dd] - qkf[ql*68 + dd]; d2 += t * t; }
    #pragma unroll
    for (int k = 0; k < 16; k++){
      double v0 = xr[16 + 3*k], v1 = xr[17 + 3*k], v2 = xr[18 + 3*k];
      #pragma unroll
      for (int a = 0; a < 3; a++){
        double val = R[a] * v0 + R[3 + a] * v1 + R[6 + a] * v2;
        double t = val - qkf[ql*68 + 16 + 3*k + a]; d2 += t * t;
      }
    }
    #pragma unroll
    for (int a = 0; a < 3; a++){ double t = (double)pos[node*3 + a] - qkf[ql*68 + 64 + a]; d2 += t * t; }

    // rank within the query's 32 lanes: (d2, j) lexicographic == ref sort order
    int base = (tid & 32) ? 32 : 0;    // half-wave base within the wave
    int rank = 0;
    #pragma unroll 1
    for (int j2 = 0; j2 < 32; j2++){
      double o = __shfl(d2, base + j2, 64);
      rank += (o < d2) || ((o == d2) && (j2 < j));
    }
    if (rank < KNN) nbrL[ql * KNN + rank] = node;
  }
  __syncthreads();   // nbrL complete; qkf dead (xs may now be written)

  // ---- gather x_src into xs (80 rows x 64 f32, stride 68) ----
  {
    int f4 = tid & 15;
    #pragma unroll
    for (int p = 0; p < 5; p++){
      int e = (tid >> 4) + (p << 4);
      float4 v = *(const float4*)&x[(size_t)nbrL[e] * 64 + (f4 << 2)];
      *(float4*)&xsF[e * 68 + (f4 << 2)] = v;
    }
  }
  __syncthreads();

  // ---- build h bf16 into hB [d>>5][e][d&31] ----
  {
    int d = tid & 127, eo = tid >> 7;   // eo 0..1
    int cls, kk = 0, aa = 0;
    if (d < 64) cls = 0;
    else { int dd = d - 64;
      if (dd < 16) cls = 1;
      else { cls = 2; int r = dd - 16; kk = (r * 21846) >> 16; aa = r - 3 * kk; } }
    int hoff = ((d >> 5) * 80) * 32 + (d & 31);
    #pragma unroll 4
    for (int p = 0; p < 40; p++){
      int e = eo + (p << 1);
      int q = (e * 3277) >> 16;       // e/20 for e<160
      float v;
      if (cls == 0) v = xdL[q * 64 + d];
      else if (cls == 1) v = xsF[e * 68 + (d - 64)] - xdL[q * 64 + (d - 64)];
      else {
        int base = 16 + 3 * kk;
        float u0 = xsF[e * 68 + base]     - xdL[q * 64 + base];
        float u1 = xsF[e * 68 + base + 1] - xdL[q * 64 + base + 1];
        float u2 = xsF[e * 68 + base + 2] - xdL[q * 64 + base + 2];
        v = lfL[q * 9 + aa * 3] * u0 + lfL[q * 9 + aa * 3 + 1] * u1 + lfL[q * 9 + aa * 3 + 2] * u2;
      }
      hB[hoff + e * 32] = f2bf_rne(v);
    }
  }
  __syncthreads();   // hB done; xs dead (a1B may now be written)

  // ---- layer 1: a1 = relu(h @ W1 + b1) ----
  {
    float b1v[2];
    b1v[0] = b1L[(wv << 5) + l15];
    b1v[1] = b1L[(wv << 5) + 16 + l15];
    #pragma unroll
    for (int mt = 0; mt < 5; mt++){
      s16x8 af[4];
      #pragma unroll
      for (int ks = 0; ks < 4; ks++)
        af[ks] = *(const s16x8*)(hB + ((ks * 80 + (mt << 4) + l15) * 32 + (quad << 3)));
      #pragma unroll
      for (int ct = 0; ct < 2; ct++){
        f32x4 acc = (f32x4){0.f, 0.f, 0.f, 0.f};
        #pragma unroll
        for (int ks = 0; ks < 4; ks++)
          acc = __builtin_amdgcn_mfma_f32_16x16x32_bf16(af[ks], wf1[ct][ks], acc, 0, 0, 0);
        #pragma unroll
        for (int r = 0; r < 4; r++){
          float v = fmaxf(acc[r] + b1v[ct], 0.f);
          int row = (mt << 4) + (quad << 2) + r;
          a1B[(wv * 80 + row) * 32 + (ct << 4) + l15] = f2bf_rne(v);
        }
      }
    }
  }
  __syncthreads();   // a1 complete

  // ---- layer 2 + max over edges (registers only) ----
  {
    float mxv[2][4];
    #pragma unroll
    for (int ct = 0; ct < 2; ct++)
      #pragma unroll
      for (int q = 0; q < 4; q++) mxv[ct][q] = -3.0e38f;
    const int QA[5]  = {0,0,1,2,3};
    const int CUT[5] = {16,4,8,12,16};
    #pragma unroll
    for (int mt = 0; mt < 5; mt++){
      s16x8 af[4];
      #pragma unroll
      for (int ks = 0; ks < 4; ks++)
        af[ks] = *(const s16x8*)(a1B + ((ks * 80 + (mt << 4) + l15) * 32 + (quad << 3)));
      int qa = QA[mt], cut = CUT[mt];
      #pragma unroll
      for (int ct = 0; ct < 2; ct++){
        f32x4 acc = (f32x4){0.f, 0.f, 0.f, 0.f};
        #pragma unroll
        for (int ks = 0; ks < 4; ks++)
          acc = __builtin_amdgcn_mfma_f32_16x16x32_bf16(af[ks], wf2[ct][ks], acc, 0, 0, 0);
        if (cut >= 16){
          #pragma unroll
          for (int r = 0; r < 4; r++) mxv[ct][qa] = fmaxf(mxv[ct][qa], acc[r]);
        } else {
          #pragma unroll
          for (int r = 0; r < 4; r++){
            int lr = (quad << 2) + r;
            bool toA = lr < cut;
            mxv[ct][qa]     = fmaxf(mxv[ct][qa],     toA ? acc[r] : -3.0e38f);
            mxv[ct][qa + 1] = fmaxf(mxv[ct][qa + 1], toA ? -3.0e38f : acc[r]);
          }
        }
      }
    }
    // combine across quads (rows) -- all lanes end with full per-col max
    #pragma unroll
    for (int ct = 0; ct < 2; ct++){
      #pragma unroll
      for (int q = 0; q < 4; q++){
        float v = mxv[ct][q];
        v = fmaxf(v, __shfl_xor(v, 16, 64));
        v = fmaxf(v, __shfl_xor(v, 32, 64));
        mxv[ct][q] = v;
      }
    }
    if (quad == 0){
      #pragma unroll
      for (int ct = 0; ct < 2; ct++){
        int col = (wv << 5) + (ct << 4) + l15;
        float b2v = b2L[col];
        #pragma unroll
        for (int q = 0; q < 4; q++)
          out[(size_t)(qid0 + q) * 128 + col] = mxv[ct][q] + b2v;
      }
    }
  }
}

// ---------------------------------------------------------------------------
// k_tail: pos[idx], batch[idx], lframes[idx] as fp32 at flat offsets.
// ---------------------------------------------------------------------------
__global__ __launch_bounds__(256) void k_tail(const float* __restrict__ pos,
    const float* __restrict__ lfr, float* __restrict__ out){
  int q = blockIdx.x * 256 + threadIdx.x;   // 0..16383
  int b = q >> 12;
  int node = (b << 14) + ((q & 4095) << 2);
  float* o_pos = out + 2097152;    // 16384*128
  float* o_bat = out + 2146304;    // + 16384*3
  float* o_lf  = out + 2162688;    // + 16384
  #pragma unroll
  for (int j = 0; j < 3; j++) o_pos[q * 3 + j] = pos[node * 3 + j];
  o_bat[q] = (float)b;
  #pragma unroll
  for (int j = 0; j < 9; j++) o_lf[q * 9 + j] = lfr[node * 9 + j];
}

extern "C" void kernel_launch(void* const* d_in, const int* in_sizes, int n_in,
                              void* d_out, int out_size, void* d_ws, size_t ws_size,
                              hipStream_t stream){
  const float* x   = (const float*)d_in[0];
  const float* pos = (const float*)d_in[1];
  const float* lfr = (const float*)d_in[2];
  // d_in[3] = batch (recomputed analytically)
  const float* W1  = (const float*)d_in[4];
  const float* b1  = (const float*)d_in[5];
  const float* W2  = (const float*)d_in[6];
  const float* b2  = (const float*)d_in[7];

  unsigned short* kfB = (unsigned short*)d_ws;
  float* normB = (float*)((char*)d_ws + WS_NORM);
  unsigned short* wb1 = (unsigned short*)((char*)d_ws + WS_WT1);
  unsigned short* wb2 = (unsigned short*)((char*)d_ws + WS_WT2);
  unsigned short* mgG = (unsigned short*)((char*)d_ws + WS_MG);
  float* out = (float*)d_out;

  hipLaunchKernelGGL(k_prep,   dim3(256),  dim3(256),  0, stream, x, pos, lfr, kfB, normB);
  hipLaunchKernelGGL(k_wprep,  dim3(64),   dim3(256),  0, stream, W1, W2, wb1, wb2);
  hipLaunchKernelGGL(k_knn,    dim3(256),  dim3(1024), 0, stream, kfB, normB, mgG);
  hipLaunchKernelGGL(k_mlp,    dim3(4096), dim3(256),  0, stream, x, pos, lfr, mgG, wb1, wb2, b1, b2, out);
  hipLaunchKernelGGL(k_tail,   dim3(64),   dim3(256),  0, stream, pos, lfr, out);
}